// Round 4
// baseline (26126.031 us; speedup 1.0000x reference)
//
#include <hip/hip_runtime.h>

typedef unsigned short u16;
typedef unsigned int u32;

#define NT 1024
#define Bv 32
#define Tv 256
#define Wv 128
#define Rv 4
#define Nv 128
#define MROW 129          // padded mem row stride (floats)
#define DELTAv 1e-6f

__device__ __forceinline__ float bf2f(u16 u){
  union { u32 i; float f; } c; c.i = ((u32)u) << 16; return c.f;
}
__device__ __forceinline__ u16 f2bf(float f){
  union { float f; u32 u; } c; c.f = f;
  u32 u = c.u;
  return (u16)((u + 0x7fffu + ((u >> 16) & 1u)) >> 16);
}
__device__ __forceinline__ void unp(u32 v, float& a, float& b){
  union { u32 i; float f; } c0, c1;
  c0.i = v << 16; c1.i = v & 0xffff0000u;
  a = c0.f; b = c1.f;
}
__device__ __forceinline__ float sigm(float x){ return 1.0f / (1.0f + __expf(-x)); }
__device__ __forceinline__ float softplusf(float x){ return fmaxf(x, 0.f) + log1pf(__expf(-fabsf(x))); }
__device__ __forceinline__ float wredsum(float v){
  #pragma unroll
  for (int o = 32; o > 0; o >>= 1) v += __shfl_down(v, o, 64);
  return v;
}
__device__ __forceinline__ float wredmax(float v){
  #pragma unroll
  for (int o = 32; o > 0; o >>= 1) v = fmaxf(v, __shfl_down(v, o, 64));
  return v;
}
__device__ __forceinline__ float ldval(const void* p, int idx, int dt32){
  return dt32 ? ((const float*)p)[idx] : bf2f(((const u16*)p)[idx]);
}

// dtype detect: flag=1 if fp32 buffer, 0 if bf16 (fp32 low-mantissa halfwords have wild exponents)
__global__ void detect_dtype(const u16* __restrict__ buf, int* __restrict__ flag){
  int lane = threadIdx.x;
  float crazy = 0.f;
  for (int i = 0; i < 4; i++){
    u16 v = buf[lane * 4 + i];
    int e = (v >> 7) & 0xFF;
    if (e != 0 && (e < 117 || e > 137)) crazy += 1.f;
  }
  crazy = wredsum(crazy);
  if (lane == 0) flag[0] = (crazy >= 32.f) ? 1 : 0;
}

// Pack W[j,k] ([Js x K]) into bf16-pair u32: dst[k2*Jd + j] = {W[j,2k2] | W[j,2k2+1]<<16}
__global__ void pack_w(const void* __restrict__ src, u32* __restrict__ dst,
                       int Js, int Jd, int K, const int* __restrict__ flag){
  int j = blockIdx.x * 256 + threadIdx.x;
  int k2 = blockIdx.y;
  if (j >= Jd) return;
  u16 lo = 0, hi = 0;
  if (j < Js){
    if (flag[0]){
      const float* s = (const float*)src;
      lo = f2bf(s[(size_t)j * K + 2 * k2]);
      hi = f2bf(s[(size_t)j * K + 2 * k2 + 1]);
    } else {
      const u16* s = (const u16*)src;
      lo = s[(size_t)j * K + 2 * k2];
      hi = s[(size_t)j * K + 2 * k2 + 1];
    }
  }
  dst[(size_t)k2 * Jd + j] = (u32)lo | ((u32)hi << 16);
}

__global__ void fill_half(u16* __restrict__ p, int n){
  int i = blockIdx.x * 256 + threadIdx.x;
  if (i < n) p[i] = 0x3F00;  // bf16 0.5 diagnostic
}

__global__ __launch_bounds__(NT) void dnc_main(
    const void* __restrict__ input,
    const void* __restrict__ enc_bih_g, const void* __restrict__ enc_bhh_g,
    const void* __restrict__ ctl_bih_g, const void* __restrict__ ctl_bhh_g,
    const void* __restrict__ iface_b_g, const void* __restrict__ out_b_g,
    const u32* __restrict__ encPW, const u32* __restrict__ ctlPW,
    const u32* __restrict__ ifPW, const u32* __restrict__ outPW,
    float* __restrict__ linkG, void* __restrict__ outp,
    const int* __restrict__ dtflag)
{
  const int b = blockIdx.x;
  const int tid = threadIdx.x;
  const int lane = tid & 63;
  const int wid = tid >> 6;
  const int dt32 = dtflag[0];

  __shared__ __align__(16) float memS[Nv * MROW];   // 66048 B, row stride 129
  __shared__ __align__(16) float pp[NT];            // GEMV partials / xi / bw partials
  __shared__ __align__(16) float xhE[256];          // [x_t ; h_enc]
  __shared__ __align__(16) float xhC[768];          // [x_ctl(640) ; h_ctl(128)]
  __shared__ __align__(16) float xoutS[640];        // [h ; rv interleaved]
  __shared__ __align__(16) float encBias[512];
  __shared__ __align__(16) float ctlBias[512];
  __shared__ __align__(16) float ifBias[NT];
  __shared__ __align__(16) float outBias[Wv];
  __shared__ __align__(16) float rvS[512];          // [r*128+w]
  __shared__ __align__(16) float rwS[512];
  __shared__ __align__(16) float rkeyS[512];
  __shared__ __align__(16) float rcS[512];
  __shared__ __align__(16) float fwS[512];
  __shared__ __align__(16) float hES[Wv], cES[Wv], hS[Wv], cS[Wv];
  __shared__ __align__(16) float wkeyS[Wv], eraseS[Wv], wvecS[Wv];
  __shared__ __align__(16) float wwS[Nv], usageS[Nv], precS[Nv], wcS[Nv];
  __shared__ __align__(16) float uS[Nv], sortedU[Nv], scanA[Nv];
  __shared__ float rstrS[Rv], fgS[Rv], rmS[3 * Rv], scal[8];

  // ---- init ----
  if (tid < 512){
    encBias[tid] = ldval(enc_bih_g, tid, dt32) + ldval(enc_bhh_g, tid, dt32);
    ctlBias[tid] = ldval(ctl_bih_g, tid, dt32) + ldval(ctl_bhh_g, tid, dt32);
    rvS[tid] = 0.f; rwS[tid] = 0.f;
  }
  ifBias[tid] = (tid < 919) ? ldval(iface_b_g, tid, dt32) : 0.f;
  if (tid < Wv){
    outBias[tid] = ldval(out_b_g, tid, dt32);
    hES[tid] = 0.f; cES[tid] = 0.f; hS[tid] = 0.f; cS[tid] = 0.f;
    usageS[tid] = 0.f; precS[tid] = 0.f; wwS[tid] = 0.f;
  }
  for (int i = tid; i < Nv * MROW; i += NT) memS[i] = 0.f;
  float* linkB = linkG + (size_t)b * Nv * Nv;
  for (int i = tid; i < Nv * Nv; i += NT) linkB[i] = 0.f;
  __syncthreads();

  for (int t = 0; t < Tv; ++t){
    // B0: stage encoder input + h
    if (tid < Wv){
      int idx = ((int)b * Tv + t) * Wv + tid;
      xhE[tid] = dt32 ? ((const float*)input)[idx] : bf2f(((const u16*)input)[idx]);
      xhE[Wv + tid] = hES[tid];
    }
    __syncthreads();

    // B1: encoder gate partials (1024 = 512 out x 2 k-halves)
    {
      int half = tid >> 9, out = tid & 511;
      float acc = 0.f;
      const u32* wp = encPW + (half * 64) * 512 + out;
      const float* xp = xhE + half * 128;
      #pragma unroll 8
      for (int q = 0; q < 64; q++){
        float w0, w1; unp(wp[q * 512], w0, w1);
        float2 x2 = *(const float2*)(xp + 2 * q);
        acc += x2.x * w0 + x2.y * w1;
      }
      pp[tid] = acc;
    }
    __syncthreads();

    // B2: encoder LSTM pointwise + build controller x
    if (tid < Wv){
      float g0 = encBias[tid]       + pp[tid]       + pp[512 + tid];
      float g1 = encBias[128 + tid] + pp[128 + tid] + pp[640 + tid];
      float g2 = encBias[256 + tid] + pp[256 + tid] + pp[768 + tid];
      float g3 = encBias[384 + tid] + pp[384 + tid] + pp[896 + tid];
      float cn = sigm(g1) * cES[tid] + sigm(g0) * tanhf(g2);
      float hn = sigm(g3) * tanhf(cn);
      cES[tid] = cn; hES[tid] = hn;
      xhC[5 * tid]     = hn;
      xhC[5 * tid + 1] = rvS[tid];
      xhC[5 * tid + 2] = rvS[128 + tid];
      xhC[5 * tid + 3] = rvS[256 + tid];
      xhC[5 * tid + 4] = rvS[384 + tid];
      xhC[640 + tid]   = hS[tid];
    }
    __syncthreads();

    // B3: controller gate partials (512 out x 2 k-halves of 192 pairs)
    {
      int half = tid >> 9, out = tid & 511;
      float acc = 0.f;
      const u32* wp = ctlPW + (half * 192) * 512 + out;
      const float* xp = xhC + half * 384;
      #pragma unroll 8
      for (int q = 0; q < 192; q++){
        float w0, w1; unp(wp[q * 512], w0, w1);
        float2 x2 = *(const float2*)(xp + 2 * q);
        acc += x2.x * w0 + x2.y * w1;
      }
      pp[tid] = acc;
    }
    __syncthreads();

    // B4: controller LSTM pointwise
    if (tid < Wv){
      float g0 = ctlBias[tid]       + pp[tid]       + pp[512 + tid];
      float g1 = ctlBias[128 + tid] + pp[128 + tid] + pp[640 + tid];
      float g2 = ctlBias[256 + tid] + pp[256 + tid] + pp[768 + tid];
      float g3 = ctlBias[384 + tid] + pp[384 + tid] + pp[896 + tid];
      float cn = sigm(g1) * cS[tid] + sigm(g0) * tanhf(g2);
      float hn = sigm(g3) * tanhf(cn);
      cS[tid] = cn; hS[tid] = hn;
    }
    __syncthreads();

    // B5: interface vector xi -> pp[0..918] (1024 outputs incl. zero pad)
    {
      float acc = ifBias[tid];
      const u32* wp = ifPW + tid;
      #pragma unroll 8
      for (int q = 0; q < 64; q++){
        float w0, w1; unp(wp[q * 1024], w0, w1);
        float2 h2 = *(const float2*)(hS + 2 * q);
        acc += h2.x * w0 + h2.y * w1;
      }
      pp[tid] = acc;
    }
    __syncthreads();

    // B6: parse interface
    if (tid < 512){
      rkeyS[tid] = tanhf(pp[tid]);
    } else if (tid < 640){ int w = tid - 512; wkeyS[w] = tanhf(pp[516 + w]);
    } else if (tid < 768){ int w = tid - 640; eraseS[w] = sigm(pp[645 + w]);
    } else if (tid < 896){ int w = tid - 768; wvecS[w] = tanhf(pp[773 + w]);
    } else if (tid < 900){ int r = tid - 896; rstrS[r] = softplusf(pp[512 + r]);
    } else if (tid < 904){ int r = tid - 900; fgS[r] = sigm(pp[901 + r]);
    } else if (tid < 908){
      int r = tid - 904;
      float m0 = pp[907 + 3 * r], m1 = pp[908 + 3 * r], m2 = pp[909 + 3 * r];
      float mx = fmaxf(m0, fmaxf(m1, m2));
      float e0 = __expf(m0 - mx), e1 = __expf(m1 - mx), e2 = __expf(m2 - mx);
      float s = e0 + e1 + e2;
      rmS[3 * r] = e0 / s; rmS[3 * r + 1] = e1 / s; rmS[3 * r + 2] = e2 / s;
    } else if (tid == 908){ scal[0] = softplusf(pp[644]);
    } else if (tid == 909){ scal[1] = sigm(pp[905]);
    } else if (tid == 910){ scal[2] = sigm(pp[906]); }
    __syncthreads();

    // B7: key norms (waves 0-4) || usage update (waves 5-6; old ww, old rw)
    if (wid < 5){
      float* arr = (wid < 4) ? (rkeyS + wid * 128) : wkeyS;
      float a = arr[lane], bq = arr[lane + 64];
      float s = wredsum(a * a + bq * bq);
      s = __shfl(s, 0, 64);
      float inv = 1.0f / (sqrtf(s) + DELTAv);
      arr[lane] = a * inv; arr[lane + 64] = bq * inv;
    } else if (wid < 7){
      int n = (wid - 5) * 64 + lane;
      float us = usageS[n];
      us = us + (1.f - us) * wwS[n];
      float ret = (1.f - fgS[0] * rwS[n]) * (1.f - fgS[1] * rwS[128 + n]) *
                  (1.f - fgS[2] * rwS[256 + n]) * (1.f - fgS[3] * rwS[384 + n]);
      usageS[n] = us * ret;
    }
    __syncthreads();

    // B8: write-content scores (wave-coop rows, old mem) + uS
    {
      int n0 = wid * 8;
      for (int k = 0; k < 8; k++){
        int n = n0 + k;
        float a = memS[n * MROW + lane], bq = memS[n * MROW + 64 + lane];
        float sq = a * a + bq * bq;
        float dt = a * wkeyS[lane] + bq * wkeyS[64 + lane];
        #pragma unroll
        for (int o = 32; o > 0; o >>= 1){ sq += __shfl_down(sq, o, 64); dt += __shfl_down(dt, o, 64); }
        if (lane == 0) wcS[n] = dt / (sqrtf(sq) + DELTAv) * scal[0];
      }
    }
    if (tid < Nv) uS[tid] = DELTAv + (1.f - DELTAv) * usageS[tid];
    __syncthreads();

    // B9: wc softmax (wave 0) || stable rank sort (tid 64..191)
    int rnk = 0;
    if (wid == 0){
      float a = wcS[lane], bq = wcS[lane + 64];
      float mx = wredmax(fmaxf(a, bq)); mx = __shfl(mx, 0, 64);
      float ea = __expf(a - mx), eb = __expf(bq - mx);
      float s = wredsum(ea + eb); s = __shfl(s, 0, 64);
      wcS[lane] = ea / s; wcS[lane + 64] = eb / s;
    } else if (tid >= 64 && tid < 192){
      int n = tid - 64;
      float un = uS[n];
      int r = 0;
      for (int m = 0; m < Nv; m++){
        float um = uS[m];
        r += (um < un) || (um == un && m < n);
      }
      rnk = r;
      sortedU[r] = un;
    }
    __syncthreads();

    // B10: inclusive cumprod scan of sortedU (single wave, 2 elems/lane)
    if (wid == 8){
      float a = sortedU[2 * lane], bq = sortedU[2 * lane + 1];
      float p = a * bq;
      float incl = p;
      #pragma unroll
      for (int o = 1; o < 64; o <<= 1){
        float tv = __shfl_up(incl, o, 64);
        if (lane >= o) incl *= tv;
      }
      float ex = __shfl_up(incl, 1, 64);
      if (lane == 0) ex = 1.f;
      scanA[2 * lane] = ex * a;
      scanA[2 * lane + 1] = ex * p;
    }
    __syncthreads();

    // B11: allocation + write weighting
    if (tid >= 64 && tid < 192){
      int n = tid - 64;
      float ex = (rnk == 0) ? 1.f : scanA[rnk - 1];
      float al = (1.f - uS[n]) * ex;
      wwS[n] = scal[2] * (scal[1] * al + (1.f - scal[1]) * wcS[n]);
    }
    __syncthreads();

    // B12: sum(ww)
    if (wid == 0){
      float s = wredsum(wwS[lane] + wwS[64 + lane]);
      if (lane == 0) scal[3] = s;
    }
    __syncthreads();

    // B13: mem erase/write (LDS) + link update (global, old prec)
    #pragma unroll
    for (int it = 0; it < 16; it++){
      int idx = it * NT + tid;
      int n = idx >> 7, w = idx & 127;
      float wwn = wwS[n];
      float m = memS[n * MROW + w];
      memS[n * MROW + w] = m * (1.f - wwn * eraseS[w]) + wwn * wvecS[w];
    }
    {
      float4* l4 = (float4*)linkB;
      #pragma unroll
      for (int it = 0; it < 4; it++){
        int e4 = it * NT + tid;
        int n = e4 >> 5, w0 = (e4 & 31) * 4;
        float wwn = wwS[n];
        float4 l = l4[e4];
        l.x = (n == w0 + 0) ? 0.f : ((1.f - wwn - wwS[w0 + 0]) * l.x + wwn * precS[w0 + 0]);
        l.y = (n == w0 + 1) ? 0.f : ((1.f - wwn - wwS[w0 + 1]) * l.y + wwn * precS[w0 + 1]);
        l.z = (n == w0 + 2) ? 0.f : ((1.f - wwn - wwS[w0 + 2]) * l.z + wwn * precS[w0 + 2]);
        l.w = (n == w0 + 3) ? 0.f : ((1.f - wwn - wwS[w0 + 3]) * l.w + wwn * precS[w0 + 3]);
        l4[e4] = l;
      }
    }
    __syncthreads();

    // B14: read-content scores (wave-coop rows, new mem) + prec update
    {
      int n0 = wid * 8;
      for (int k = 0; k < 8; k++){
        int n = n0 + k;
        float a = memS[n * MROW + lane], bq = memS[n * MROW + 64 + lane];
        float sq = a * a + bq * bq;
        float d0 = a * rkeyS[lane]       + bq * rkeyS[64 + lane];
        float d1 = a * rkeyS[128 + lane] + bq * rkeyS[192 + lane];
        float d2 = a * rkeyS[256 + lane] + bq * rkeyS[320 + lane];
        float d3 = a * rkeyS[384 + lane] + bq * rkeyS[448 + lane];
        #pragma unroll
        for (int o = 32; o > 0; o >>= 1){
          sq += __shfl_down(sq, o, 64);
          d0 += __shfl_down(d0, o, 64); d1 += __shfl_down(d1, o, 64);
          d2 += __shfl_down(d2, o, 64); d3 += __shfl_down(d3, o, 64);
        }
        if (lane == 0){
          float inv = 1.f / (sqrtf(sq) + DELTAv);
          rcS[n]       = d0 * inv * rstrS[0];
          rcS[128 + n] = d1 * inv * rstrS[1];
          rcS[256 + n] = d2 * inv * rstrS[2];
          rcS[384 + n] = d3 * inv * rstrS[3];
        }
      }
    }
    if (tid < Nv) precS[tid] = (1.f - scal[3]) * precS[tid] + wwS[tid];
    __syncthreads();

    // B15: per-head rc softmax (waves 0-3)
    if (wid < 4){
      float a = rcS[wid * 128 + lane], bq = rcS[wid * 128 + 64 + lane];
      float mx = wredmax(fmaxf(a, bq)); mx = __shfl(mx, 0, 64);
      float ea = __expf(a - mx), eb = __expf(bq - mx);
      float s = wredsum(ea + eb); s = __shfl(s, 0, 64);
      rcS[wid * 128 + lane] = ea / s; rcS[wid * 128 + 64 + lane] = eb / s;
    }
    __syncthreads();

    // B16: fw (wave-coop, link rows) + bw (k-split, link cols); old rw
    {
      for (int k = 0; k < 32; k++){
        int o = wid * 32 + k;
        int r = o >> 7, i = o & 127;
        float la = linkB[i * 128 + lane], lb = linkB[i * 128 + 64 + lane];
        float acc = la * rwS[r * 128 + lane] + lb * rwS[r * 128 + 64 + lane];
        acc = wredsum(acc);
        if (lane == 0) fwS[o] = acc;
      }
      int h = tid >> 9, o = tid & 511, r = o >> 7, i = o & 127;
      float acc = 0.f;
      #pragma unroll 8
      for (int q = 0; q < 64; q++){
        int j = h * 64 + q;
        acc += rwS[r * 128 + j] * linkB[j * 128 + i];
      }
      pp[tid] = acc;
    }
    __syncthreads();

    // B17: new read weights
    if (tid < 512){
      int r = tid >> 7;
      float bw = pp[tid] + pp[512 + tid];
      rwS[tid] = rmS[3 * r] * bw + rmS[3 * r + 1] * fwS[tid] + rmS[3 * r + 2] * rcS[tid];
    }
    __syncthreads();

    // B18: read vectors rv[r][w] partials (k-split over n)
    {
      int h = tid >> 9, o = tid & 511, r = o >> 7, w = o & 127;
      float acc = 0.f;
      #pragma unroll 8
      for (int q = 0; q < 64; q++){
        int n = h * 64 + q;
        acc += rwS[r * 128 + n] * memS[n * MROW + w];
      }
      pp[tid] = acc;
    }
    __syncthreads();

    // B19: combine rv + build output vector
    if (tid < 512){
      int r = tid >> 7, w = tid & 127;
      float rv = pp[tid] + pp[512 + tid];
      rvS[tid] = rv;
      xoutS[128 + 4 * w + r] = rv;
    } else if (tid < 640){
      xoutS[tid - 512] = hS[tid - 512];
    }
    __syncthreads();

    // B20: output projection partials (128 out x 8 k-splits of 40 pairs)
    {
      int s = tid >> 7, j = tid & 127;
      float acc = 0.f;
      const u32* wp = outPW + (s * 40) * 128 + j;
      const float* xp = xoutS + s * 80;
      #pragma unroll 8
      for (int q = 0; q < 40; q++){
        float w0, w1; unp(wp[q * 128], w0, w1);
        float2 x2 = *(const float2*)(xp + 2 * q);
        acc += x2.x * w0 + x2.y * w1;
      }
      pp[tid] = acc;
    }
    __syncthreads();

    // B21: store output
    if (tid < Wv){
      float o = outBias[tid];
      #pragma unroll
      for (int s = 0; s < 8; s++) o += pp[s * 128 + tid];
      size_t oi = ((size_t)b * Tv + t) * Wv + tid;
      if (dt32) ((float*)outp)[oi] = o;
      else ((u16*)outp)[oi] = f2bf(o);
    }
    __syncthreads();
  }
}

extern "C" void kernel_launch(void* const* d_in, const int* in_sizes, int n_in,
                              void* d_out, int out_size, void* d_ws, size_t ws_size,
                              hipStream_t stream) {
  (void)in_sizes; (void)n_in;
  const void* input   = d_in[0];
  const void* enc_Wih = d_in[2];
  const void* enc_Whh = d_in[3];
  const void* enc_bih = d_in[4];
  const void* enc_bhh = d_in[5];
  const void* ctl_Wih = d_in[6];
  const void* ctl_Whh = d_in[7];
  const void* ctl_bih = d_in[8];
  const void* ctl_bhh = d_in[9];
  const void* iface_W = d_in[10];
  const void* iface_b = d_in[11];
  const void* out_W   = d_in[12];
  const void* out_b   = d_in[13];

  char* ws = (char*)d_ws;
  size_t off = 0;
  int* dtflag = (int*)(ws + off); off += 16;
  u32* encPW = (u32*)(ws + off); off += (size_t)128 * 512 * 4;   // [k2<64: Wih][64..128: Whh]
  u32* ctlPW = (u32*)(ws + off); off += (size_t)384 * 512 * 4;   // [0..320: Wih][320..384: Whh]
  u32* ifPW  = (u32*)(ws + off); off += (size_t)64 * 1024 * 4;   // padded to 1024 outputs
  u32* outPW = (u32*)(ws + off); off += (size_t)320 * 128 * 4;
  float* linkG = (float*)(ws + off); off += (size_t)Bv * Nv * Nv * 4;
  const size_t need_bytes = off;  // ~3.57 MB

  if (ws_size < need_bytes){
    fill_half<<<dim3((out_size + 255) / 256), dim3(256), 0, stream>>>((u16*)d_out, out_size);
    return;
  }

  detect_dtype<<<dim3(1), dim3(64), 0, stream>>>((const u16*)input, dtflag);

  pack_w<<<dim3(2, 64), 256, 0, stream>>>(enc_Wih, encPW, 512, 512, 128, dtflag);
  pack_w<<<dim3(2, 64), 256, 0, stream>>>(enc_Whh, encPW + 64 * 512, 512, 512, 128, dtflag);
  pack_w<<<dim3(2, 320), 256, 0, stream>>>(ctl_Wih, ctlPW, 512, 512, 640, dtflag);
  pack_w<<<dim3(2, 64), 256, 0, stream>>>(ctl_Whh, ctlPW + 320 * 512, 512, 512, 128, dtflag);
  pack_w<<<dim3(4, 64), 256, 0, stream>>>(iface_W, ifPW, 919, 1024, 128, dtflag);
  pack_w<<<dim3(1, 320), 256, 0, stream>>>(out_W, outPW, 128, 128, 640, dtflag);

  dnc_main<<<dim3(Bv), dim3(NT), 0, stream>>>(
      input, enc_bih, enc_bhh, ctl_bih, ctl_bhh, iface_b, out_b,
      encPW, ctlPW, ifPW, outPW, linkG, d_out, dtflag);
}